// Round 9
// baseline (1074.581 us; speedup 1.0000x reference)
//
#include <hip/hip_runtime.h>

// GroupAwareEncoder: 2-layer graph propagation (LightGCN-style).
//   per layer: h[c] = sum_{i: cols[i]=c} vals[i] * X[rows[i]]      (E x D)
//              Y[r] = sum_{i: rows[i]=r} vals[i] * h[cols[i]]      (N x D)
//              Y    = leaky_relu(Y, slope=0.5)
// Output = final Y (N x D) flat.
//
// R5 evidence: fill 8x write-amplified (WRITE 286MB vs 38MB payload).
// Mechanism: COO read stream cycles the 4MB per-XCD L2 ~7x per pass, evicting
// partially-filled dirty edge lines. Fix: (a) split fill into e-pass/n-pass so
// dirty region = 2.4MB < L2; (b) nontemporal loads for the COO stream so reads
// don't displace dirty lines; (c) read payload only for in-partition edges.
// R8: nt-load of struct Edge* rejected by clang -> load as long long + unpack.

constexpr int D = 64;
constexpr float SLOPE = 0.5f;
constexpr int NPART = 8;

struct Edge { int src; float val; };   // 8 bytes; bit-identical to long long

__device__ __forceinline__ void unpack_edge(long long w, int& src, float& val) {
    src = (int)(unsigned)(w & 0xffffffffLL);
    val = __int_as_float((int)(unsigned)((unsigned long long)w >> 32));
}

// ---------------- degree histogram ----------------

__global__ __launch_bounds__(256) void hist_kernel(
    const int* __restrict__ rows, const int* __restrict__ cols,
    int* __restrict__ deg_n, int* __restrict__ deg_e, int nnz)
{
    int t = blockIdx.x * blockDim.x + threadIdx.x;
    if (t >= nnz) return;
    atomicAdd(&deg_n[rows[t]], 1);
    atomicAdd(&deg_e[cols[t]], 1);
}

// ---------------- 3-phase exclusive scan (1024 elems/block) ----------------

__global__ __launch_bounds__(256) void scan_phase1(
    const int* __restrict__ deg, int* __restrict__ partials, int n)
{
    __shared__ int red[256];
    int tid = threadIdx.x;
    int base = blockIdx.x * 1024 + tid * 4;
    int s = 0;
    #pragma unroll
    for (int k = 0; k < 4; ++k) {
        int i = base + k;
        if (i < n) s += deg[i];
    }
    red[tid] = s;
    __syncthreads();
    for (int d = 128; d > 0; d >>= 1) {
        if (tid < d) red[tid] += red[tid + d];
        __syncthreads();
    }
    if (tid == 0) partials[blockIdx.x] = red[0];
}

__global__ __launch_bounds__(256) void scan_phase2(
    int* __restrict__ partials, int nb, int* __restrict__ off, int n)
{
    __shared__ int part[256];
    int tid = threadIdx.x;
    part[tid] = (tid < nb) ? partials[tid] : 0;
    __syncthreads();
    for (int d = 1; d < 256; d <<= 1) {
        int v = (tid >= d) ? part[tid - d] : 0;
        __syncthreads();
        part[tid] += v;
        __syncthreads();
    }
    if (tid < nb) partials[tid] = (tid == 0) ? 0 : part[tid - 1];
    if (tid == 255) off[n] = part[255];
}

__global__ __launch_bounds__(256) void scan_phase3(
    const int* __restrict__ deg, const int* __restrict__ partials,
    int* __restrict__ off, int* __restrict__ cur, int n)
{
    __shared__ int part[256];
    int tid = threadIdx.x;
    int base = blockIdx.x * 1024 + tid * 4;
    int d0 = 0, d1 = 0, d2 = 0, d3 = 0;
    if (base     < n) d0 = deg[base];
    if (base + 1 < n) d1 = deg[base + 1];
    if (base + 2 < n) d2 = deg[base + 2];
    if (base + 3 < n) d3 = deg[base + 3];
    part[tid] = d0 + d1 + d2 + d3;
    __syncthreads();
    for (int d = 1; d < 256; d <<= 1) {
        int v = (tid >= d) ? part[tid - d] : 0;
        __syncthreads();
        part[tid] += v;
        __syncthreads();
    }
    int p = ((tid == 0) ? 0 : part[tid - 1]) + partials[blockIdx.x];
    if (base     < n) { off[base]     = p; cur[base]     = p; p += d0; }
    if (base + 1 < n) { off[base + 1] = p; cur[base + 1] = p; p += d1; }
    if (base + 2 < n) { off[base + 2] = p; cur[base + 2] = p; p += d2; }
    if (base + 3 < n) { off[base + 3] = p; cur[base + 3] = p; }
}

// ---------------- XCD-partitioned counting-sort fill (one list/pass) -------
// Partition p = blockIdx&7 appends only edges whose KEY is in [p*S,(p+1)*S).
// nt loads: COO stream must not displace the partition's dirty edge lines.
__global__ __launch_bounds__(256) void fill_list_kernel(
    const int* __restrict__ key, const int* __restrict__ other,
    const float* __restrict__ vals,
    int* __restrict__ cur, Edge* __restrict__ edges,
    int nnz, int S)
{
    int part   = blockIdx.x & (NPART - 1);
    int chunk  = blockIdx.x >> 3;
    int nchunk = gridDim.x >> 3;
    int lo = part * S, hi = lo + S;

    for (int t = chunk * blockDim.x + threadIdx.x; t < nnz;
         t += nchunk * blockDim.x) {
        int k = __builtin_nontemporal_load(key + t);
        if (k >= lo && k < hi) {
            int   o = __builtin_nontemporal_load(other + t);
            float v = __builtin_nontemporal_load(vals + t);
            int p = atomicAdd(&cur[k], 1);
            Edge e; e.src = o; e.val = v;
            edges[p] = e;                    // normal store: accumulate in L2
        }
    }
}

// ---------------- gather-side SpMM ----------------
// One wave64 per output row; lane owns one dim; register accumulate.
// Edge stream nt-loaded as long long (read once; don't pollute L2).
__global__ __launch_bounds__(256) void spmm_gather(
    const int* __restrict__ off, const Edge* __restrict__ edges,
    const float* __restrict__ X, float* __restrict__ out,
    int nrows, int leaky)
{
    int wid = (blockIdx.x * blockDim.x + threadIdx.x) >> 6;
    if (wid >= nrows) return;
    int lane = threadIdx.x & 63;

    const long long* ew = reinterpret_cast<const long long*>(edges);

    int b = __builtin_nontemporal_load(off + wid);
    int e = __builtin_nontemporal_load(off + wid + 1);
    float acc = 0.f;
    int i = b;
    for (; i + 4 <= e; i += 4) {
        long long w0 = __builtin_nontemporal_load(ew + i);
        long long w1 = __builtin_nontemporal_load(ew + i + 1);
        long long w2 = __builtin_nontemporal_load(ew + i + 2);
        long long w3 = __builtin_nontemporal_load(ew + i + 3);
        int s0, s1, s2, s3; float v0, v1, v2, v3;
        unpack_edge(w0, s0, v0);
        unpack_edge(w1, s1, v1);
        unpack_edge(w2, s2, v2);
        unpack_edge(w3, s3, v3);
        float x0 = X[(size_t)s0 * D + lane];
        float x1 = X[(size_t)s1 * D + lane];
        float x2 = X[(size_t)s2 * D + lane];
        float x3 = X[(size_t)s3 * D + lane];
        acc += v0 * x0;
        acc += v1 * x1;
        acc += v2 * x2;
        acc += v3 * x3;
    }
    for (; i < e; ++i) {
        long long w0 = __builtin_nontemporal_load(ew + i);
        int s0; float v0;
        unpack_edge(w0, s0, v0);
        acc += v0 * X[(size_t)s0 * D + lane];
    }
    if (leaky) acc = acc >= 0.f ? acc : SLOPE * acc;
    out[(size_t)wid * D + lane] = acc;
}

// ---------------- launch ----------------

extern "C" void kernel_launch(void* const* d_in, const int* in_sizes, int n_in,
                              void* d_out, int out_size, void* d_ws, size_t ws_size,
                              hipStream_t stream)
{
    const float* ego  = (const float*)d_in[0];   // N x D
    const float* vals = (const float*)d_in[1];   // NNZ
    const int*   rows = (const int*)d_in[2];     // NNZ, in [0, N)
    const int*   cols = (const int*)d_in[3];     // NNZ, in [0, E)

    const int nnz = in_sizes[1];                 // 2,400,000
    const int N   = out_size / D;                // 150,000
    const int E   = 100000;                      // n_edges

    float* outf = (float*)d_out;

    auto align16 = [](size_t x) { return (x + 15) & ~(size_t)15; };
    size_t o = 0;
    size_t edges_e_off = o; o += align16((size_t)nnz * sizeof(Edge));
    size_t edges_n_off = o; o += align16((size_t)nnz * sizeof(Edge));
    size_t off_e_off   = o; o += align16((size_t)(E + 1) * sizeof(int));
    size_t off_n_off   = o; o += align16((size_t)(N + 1) * sizeof(int));
    size_t cur_e_off   = o; o += align16((size_t)E * sizeof(int));
    size_t cur_n_off   = o; o += align16((size_t)N * sizeof(int));
    size_t part_e_off  = o; o += align16(256 * sizeof(int));
    size_t part_n_off  = o; o += align16(256 * sizeof(int));
    size_t h_off       = o; o += align16((size_t)E * D * sizeof(float));
    size_t embs_off    = o; o += align16((size_t)N * D * sizeof(float));
    size_t need = o;

    char* ws = (char*)d_ws;

    if (ws_size >= need) {
        Edge*  edges_e = (Edge*)(ws + edges_e_off);
        Edge*  edges_n = (Edge*)(ws + edges_n_off);
        int*   off_e   = (int*)(ws + off_e_off);
        int*   off_n   = (int*)(ws + off_n_off);
        int*   cur_e   = (int*)(ws + cur_e_off);
        int*   cur_n   = (int*)(ws + cur_n_off);
        int*   part_e  = (int*)(ws + part_e_off);
        int*   part_n  = (int*)(ws + part_n_off);
        float* h       = (float*)(ws + h_off);
        float* embs    = (float*)(ws + embs_off);

        const int nb_edge = (nnz + 255) / 256;
        const int nb_sc_e = (E + 1023) / 1024;   // 98
        const int nb_sc_n = (N + 1023) / 1024;   // 147

        (void)hipMemsetAsync(cur_e, 0, (size_t)E * sizeof(int), stream);
        (void)hipMemsetAsync(cur_n, 0, (size_t)N * sizeof(int), stream);
        hist_kernel<<<nb_edge, 256, 0, stream>>>(rows, cols, cur_n, cur_e, nnz);

        scan_phase1<<<nb_sc_e, 256, 0, stream>>>(cur_e, part_e, E);
        scan_phase1<<<nb_sc_n, 256, 0, stream>>>(cur_n, part_n, N);
        scan_phase2<<<1, 256, 0, stream>>>(part_e, nb_sc_e, off_e, E);
        scan_phase2<<<1, 256, 0, stream>>>(part_n, nb_sc_n, off_n, N);
        scan_phase3<<<nb_sc_e, 256, 0, stream>>>(cur_e, part_e, off_e, cur_e, E);
        scan_phase3<<<nb_sc_n, 256, 0, stream>>>(cur_n, part_n, off_n, cur_n, N);

        // two fill passes: dirty region 2.4MB/XCD each, nt-protected
        const int SE = (E + NPART - 1) / NPART;  // 12500
        const int SN = (N + NPART - 1) / NPART;  // 18750
        fill_list_kernel<<<1024, 256, 0, stream>>>(cols, rows, vals,
                                                   cur_e, edges_e, nnz, SE);
        fill_list_kernel<<<1024, 256, 0, stream>>>(rows, cols, vals,
                                                   cur_n, edges_n, nnz, SN);

        const int nb_spmm_e = (E * 64 + 255) / 256;
        const int nb_spmm_n = (N * 64 + 255) / 256;

        const float* X = ego;
        for (int layer = 0; layer < 2; ++layer) {
            float* Y = (layer == 0) ? embs : outf;
            spmm_gather<<<nb_spmm_e, 256, 0, stream>>>(off_e, edges_e, X, h, E, 0);
            spmm_gather<<<nb_spmm_n, 256, 0, stream>>>(off_n, edges_n, h, Y, N, 1);
            X = Y;
        }
    } else {
        // safety net (ws was sufficient in rounds 4-5): zero the output
        (void)hipMemsetAsync(outf, 0, (size_t)out_size * sizeof(float), stream);
    }
}